// Round 9
// baseline (154.853 us; speedup 1.0000x reference)
//
#include <hip/hip_runtime.h>
#include <hip/hip_fp16.h>

#define NN 50000
#define FEAT 128

// Zero hist (grid-wide) + detect int64-vs-int32 edge storage (block 0).
__global__ void init_kernel(const unsigned int* ei32, int* flag, int* hist, int n) {
    int i = blockIdx.x * 256 + threadIdx.x;
    if (i < n) hist[i] = 0;
    if (blockIdx.x == 0) {
        __shared__ int ok;
        if (threadIdx.x == 0) ok = 1;
        __syncthreads();
        if (ei32[2 * threadIdx.x + 1] != 0u) ok = 0;   // benign race: all writers write 0
        __syncthreads();
        if (threadIdx.x == 0) *flag = ok;
    }
}

static __device__ __forceinline__ void load_edge(const void* ei, int is64, int E, int e,
                                                 int& src, int& dst) {
    if (is64) {
        const long long* p = (const long long*)ei;
        src = (int)p[e];
        dst = (int)p[E + e];
    } else {
        const int* p = (const int*)ei;
        src = p[e];
        dst = p[E + e];
    }
}

// ---------------- CSR build (4 edges/thread for atomic ILP) ----------------
__global__ void hist_kernel(const void* ei, const int* flag, int* hist, int E) {
    int base = (blockIdx.x * blockDim.x + threadIdx.x) * 4;
    if (base >= E) return;
    const int is64 = *flag;
    int n = E - base; if (n > 4) n = 4;
    int src[4], dst[4];
    #pragma unroll
    for (int i = 0; i < 4; ++i)
        if (i < n) load_edge(ei, is64, E, base + i, src[i], dst[i]);
    #pragma unroll
    for (int i = 0; i < 4; ++i)
        if (i < n) atomicAdd(&hist[dst[i]], 1);
}

// phase 1: per-block (256) scan -> local excl offsets + block sums + dinv (fused)
__global__ void scan_local_kernel(const int* __restrict__ hist, int* __restrict__ local_excl,
                                  int* __restrict__ bsum, float* __restrict__ dinv, int n) {
    __shared__ int sdata[256];
    int i = blockIdx.x * 256 + threadIdx.x;
    int v = (i < n) ? hist[i] : 0;
    if (i < n) dinv[i] = (v > 0) ? rsqrtf((float)v) : 0.0f;
    sdata[threadIdx.x] = v;
    __syncthreads();
    for (int d = 1; d < 256; d <<= 1) {
        int t = (threadIdx.x >= (unsigned)d) ? sdata[threadIdx.x - d] : 0;
        __syncthreads();
        sdata[threadIdx.x] += t;
        __syncthreads();
    }
    if (i < n) local_excl[i] = sdata[threadIdx.x] - v;
    if (threadIdx.x == 255) bsum[blockIdx.x] = sdata[255];
}

// phase 2: single-block exclusive scan of block sums (nb <= 1024)
__global__ void scan_bsum_kernel(int* bsum, int nb) {
    __shared__ int sdata[1024];
    int v = ((int)threadIdx.x < nb) ? bsum[threadIdx.x] : 0;
    sdata[threadIdx.x] = v;
    __syncthreads();
    for (int d = 1; d < 1024; d <<= 1) {
        int t = (threadIdx.x >= (unsigned)d) ? sdata[threadIdx.x - d] : 0;
        __syncthreads();
        sdata[threadIdx.x] += t;
        __syncthreads();
    }
    if ((int)threadIdx.x < nb) bsum[threadIdx.x] = sdata[threadIdx.x] - v;
}

// phase 3: add block offsets -> row_ptr + cursor; thread 0 writes row_ptr[n]=E
__global__ void scan_add_kernel(const int* __restrict__ local_excl, const int* __restrict__ bsum,
                                int* __restrict__ rowp, int* __restrict__ curs, int n, int E) {
    int i = blockIdx.x * 256 + threadIdx.x;
    if (i < n) {
        int r = local_excl[i] + bsum[i >> 8];
        rowp[i] = r;
        curs[i] = r;
    }
    if (i == 0) rowp[n] = E;
}

// scatter {src, weight} packed 8B; 4 edges/thread for ILP on the atomic round-trip
__global__ void scatter_kernel(const void* ei, const int* flag, int* cursor,
                               unsigned long long* __restrict__ edge,
                               const float* __restrict__ dinv, int E) {
    int base = (blockIdx.x * blockDim.x + threadIdx.x) * 4;
    if (base >= E) return;
    const int is64 = *flag;
    int n = E - base; if (n > 4) n = 4;

    int src[4], dst[4];
    #pragma unroll
    for (int i = 0; i < 4; ++i)
        if (i < n) load_edge(ei, is64, E, base + i, src[i], dst[i]);

    float ds[4], dd[4];
    #pragma unroll
    for (int i = 0; i < 4; ++i)
        if (i < n) { ds[i] = dinv[src[i]]; dd[i] = dinv[dst[i]]; }

    int pos[4];
    #pragma unroll
    for (int i = 0; i < 4; ++i)
        if (i < n) pos[i] = atomicAdd(&cursor[dst[i]], 1);

    #pragma unroll
    for (int i = 0; i < 4; ++i)
        if (i < n) {
            float w = ds[i] * dd[i];
            edge[pos[i]] = (unsigned long long)(unsigned int)src[i] |
                           ((unsigned long long)(unsigned int)__float_as_int(w) << 32);
        }
}

static __device__ __forceinline__ float4 relu4(float4 v) {
    v.x = fmaxf(v.x, 0.0f); v.y = fmaxf(v.y, 0.0f);
    v.z = fmaxf(v.z, 0.0f); v.w = fmaxf(v.w, 0.0f);
    return v;
}

static __device__ __forceinline__ void fma4(float4& a, float w, float4 v) {
    a.x += w * v.x; a.y += w * v.y; a.z += w * v.z; a.w += w * v.w;
}

static __device__ __forceinline__ float4 h4_to_f4(uint2 r) {
    __half2 lo = *reinterpret_cast<__half2*>(&r.x);
    __half2 hi = *reinterpret_cast<__half2*>(&r.y);
    float2 f0 = __half22float2(lo);
    float2 f1 = __half22float2(hi);
    return make_float4(f0.x, f0.y, f1.x, f1.y);
}

static __device__ __forceinline__ uint2 f4_to_h4(float4 v) {
    __half2 lo = __floats2half2_rn(v.x, v.y);
    __half2 hi = __floats2half2_rn(v.z, v.w);
    uint2 r;
    r.x = *reinterpret_cast<unsigned int*>(&lo);
    r.y = *reinterpret_cast<unsigned int*>(&hi);
    return r;
}

// convert fp32 features -> fp16 rows
__global__ void cvt_f2h_kernel(const float4* __restrict__ in, uint2* __restrict__ outh, int n4) {
    int i = blockIdx.x * blockDim.x + threadIdx.x;
    if (i >= n4) return;
    outh[i] = f4_to_h4(in[i]);
}

// ---------------- CSR conv (fp16 gather, fp32 accum, ReLU fused into store) ----------------
template <bool OUT_HALF>
__global__ void conv_h_kernel(const uint2* __restrict__ xh,
                              const int* __restrict__ row_ptr,
                              const unsigned long long* __restrict__ edge,
                              void* __restrict__ outbuf) {
    int gid = blockIdx.x * blockDim.x + threadIdx.x;
    int node = gid >> 5;
    int f4   = gid & 31;
    if (node >= NN) return;
    int beg = row_ptr[node];
    int end = row_ptr[node + 1];

    float4 a0 = make_float4(0.f, 0.f, 0.f, 0.f);
    float4 a1 = a0, a2 = a0, a3 = a0;

    for (int cb = beg; cb < end; cb += 32) {
        int rem = end - cb;
        if (rem > 32) rem = 32;
        int myi = (f4 < rem) ? f4 : 0;
        unsigned long long pk = edge[cb + myi];   // one coalesced 8B load / lane

        for (int j = 0; j < rem; j += 8) {
            int i0 = j + 0, i1 = j + 1, i2 = j + 2, i3 = j + 3;
            int i4 = j + 4, i5 = j + 5, i6 = j + 6, i7 = j + 7;
            int last = rem - 1;
            unsigned long long l0 = __shfl(pk, i0 < rem ? i0 : last, 32);
            unsigned long long l1 = __shfl(pk, i1 < rem ? i1 : last, 32);
            unsigned long long l2 = __shfl(pk, i2 < rem ? i2 : last, 32);
            unsigned long long l3 = __shfl(pk, i3 < rem ? i3 : last, 32);
            unsigned long long l4 = __shfl(pk, i4 < rem ? i4 : last, 32);
            unsigned long long l5 = __shfl(pk, i5 < rem ? i5 : last, 32);
            unsigned long long l6 = __shfl(pk, i6 < rem ? i6 : last, 32);
            unsigned long long l7 = __shfl(pk, i7 < rem ? i7 : last, 32);

            float w0 = (i0 < rem) ? __int_as_float((int)(l0 >> 32)) : 0.0f;
            float w1 = (i1 < rem) ? __int_as_float((int)(l1 >> 32)) : 0.0f;
            float w2 = (i2 < rem) ? __int_as_float((int)(l2 >> 32)) : 0.0f;
            float w3 = (i3 < rem) ? __int_as_float((int)(l3 >> 32)) : 0.0f;
            float w4 = (i4 < rem) ? __int_as_float((int)(l4 >> 32)) : 0.0f;
            float w5 = (i5 < rem) ? __int_as_float((int)(l5 >> 32)) : 0.0f;
            float w6 = (i6 < rem) ? __int_as_float((int)(l6 >> 32)) : 0.0f;
            float w7 = (i7 < rem) ? __int_as_float((int)(l7 >> 32)) : 0.0f;

            uint2 r0 = xh[(int)(unsigned int)l0 * 32 + f4];
            uint2 r1 = xh[(int)(unsigned int)l1 * 32 + f4];
            uint2 r2 = xh[(int)(unsigned int)l2 * 32 + f4];
            uint2 r3 = xh[(int)(unsigned int)l3 * 32 + f4];
            uint2 r4 = xh[(int)(unsigned int)l4 * 32 + f4];
            uint2 r5 = xh[(int)(unsigned int)l5 * 32 + f4];
            uint2 r6 = xh[(int)(unsigned int)l6 * 32 + f4];
            uint2 r7 = xh[(int)(unsigned int)l7 * 32 + f4];

            fma4(a0, w0, h4_to_f4(r0));
            fma4(a1, w1, h4_to_f4(r1));
            fma4(a2, w2, h4_to_f4(r2));
            fma4(a3, w3, h4_to_f4(r3));
            fma4(a0, w4, h4_to_f4(r4));
            fma4(a1, w5, h4_to_f4(r5));
            fma4(a2, w6, h4_to_f4(r6));
            fma4(a3, w7, h4_to_f4(r7));
        }
    }

    float4 acc;
    acc.x = (a0.x + a1.x) + (a2.x + a3.x);
    acc.y = (a0.y + a1.y) + (a2.y + a3.y);
    acc.z = (a0.z + a1.z) + (a2.z + a3.z);
    acc.w = (a0.w + a1.w) + (a2.w + a3.w);
    acc = relu4(acc);   // every layer output is ReLU'd

    if (OUT_HALF) {
        ((uint2*)outbuf)[node * 32 + f4] = f4_to_h4(acc);
    } else {
        ((float4*)outbuf)[node * 32 + f4] = acc;
    }
}

// ---------------- fallback (atomic) path kernels ----------------
__global__ void deg_kernel(const void* ei, const int* flag, float* deg, int E) {
    int e = blockIdx.x * blockDim.x + threadIdx.x;
    if (e >= E) return;
    int src, dst;
    load_edge(ei, *flag, E, e, src, dst);
    atomicAdd(&deg[dst], 1.0f);
}

__global__ void dinv_kernel(float* deg) {
    int i = blockIdx.x * blockDim.x + threadIdx.x;
    if (i >= NN) return;
    float d = deg[i];
    deg[i] = (d > 0.0f) ? (1.0f / sqrtf(d)) : 0.0f;
}

template <bool RELU_IN>
__global__ void conv_atomic_kernel(const float* __restrict__ xin, const void* ei, const int* flag,
                                   const float* __restrict__ dinv, float* __restrict__ yout, int E) {
    int gid = blockIdx.x * blockDim.x + threadIdx.x;
    int e  = gid >> 5;
    int f4 = gid & 31;
    if (e >= E) return;
    int src, dst;
    load_edge(ei, *flag, E, e, src, dst);
    float w = dinv[src] * dinv[dst];
    float4 v = ((const float4*)xin)[src * 32 + f4];
    if (RELU_IN) v = relu4(v);
    float* o = yout + (size_t)dst * FEAT + f4 * 4;
    atomicAdd(o + 0, v.x * w);
    atomicAdd(o + 1, v.y * w);
    atomicAdd(o + 2, v.z * w);
    atomicAdd(o + 3, v.w * w);
}

__global__ void relu_kernel(float4* buf, int n4) {
    int i = blockIdx.x * blockDim.x + threadIdx.x;
    if (i >= n4) return;
    buf[i] = relu4(buf[i]);
}

extern "C" void kernel_launch(void* const* d_in, const int* in_sizes, int n_in,
                              void* d_out, int out_size, void* d_ws, size_t ws_size,
                              hipStream_t stream) {
    const float* x  = (const float*)d_in[0];
    const void*  ei = d_in[1];
    const int E = in_sizes[1] / 2;

    float* out = (float*)d_out;
    char*  ws  = (char*)d_ws;

    const size_t feat_bytes  = (size_t)NN * FEAT * sizeof(float);
    const size_t half_bytes  = (size_t)NN * FEAT * sizeof(unsigned short);
    const int NB = (NN + 255) / 256;
    const int N4 = NN * 32;

    // ws layout (CSR fp16 path)
    const size_t OFF_FLAG = 0;
    const size_t OFF_HIST = 1024;
    const size_t OFF_DINV = OFF_HIST + (((size_t)NN * 4 + 255) & ~255ull);
    const size_t OFF_ROWP = OFF_DINV + (((size_t)NN * 4 + 255) & ~255ull);
    const size_t OFF_CURS = OFF_ROWP + ((((size_t)NN + 1) * 4 + 255) & ~255ull);
    const size_t OFF_BSUM = OFF_CURS + (((size_t)NN * 4 + 255) & ~255ull);
    const size_t OFF_EDG  = OFF_BSUM + ((1024 * 4 + 255) & ~255ull);
    const size_t OFF_HA   = OFF_EDG + (((size_t)E * 8 + 255) & ~255ull);
    const size_t OFF_HB   = OFF_HA + ((half_bytes + 255) & ~255ull);
    const size_t NEEDED   = OFF_HB + half_bytes;

    int* flag = (int*)(ws + OFF_FLAG);

    if (ws_size >= NEEDED) {
        int*   hist = (int*)(ws + OFF_HIST);
        float* dinv = (float*)(ws + OFF_DINV);
        int*   rowp = (int*)(ws + OFF_ROWP);
        int*   curs = (int*)(ws + OFF_CURS);
        int*   bsum = (int*)(ws + OFF_BSUM);
        unsigned long long* edge = (unsigned long long*)(ws + OFF_EDG);
        uint2* hA   = (uint2*)(ws + OFF_HA);
        uint2* hB   = (uint2*)(ws + OFF_HB);

        init_kernel<<<NB, 256, 0, stream>>>((const unsigned int*)ei, flag, hist, NN);

        const int e4_blocks = (E / 4 + 255) / 256 + 1;
        hist_kernel<<<e4_blocks, 256, 0, stream>>>(ei, flag, hist, E);
        scan_local_kernel<<<NB, 256, 0, stream>>>(hist, rowp, bsum, dinv, NN);
        scan_bsum_kernel<<<1, 1024, 0, stream>>>(bsum, NB);
        scan_add_kernel<<<NB, 256, 0, stream>>>(rowp, bsum, rowp, curs, NN, E);
        scatter_kernel<<<e4_blocks, 256, 0, stream>>>(ei, flag, curs, edge, dinv, E);

        cvt_f2h_kernel<<<(N4 + 255) / 256, 256, 0, stream>>>((const float4*)x, hA, N4);

        const int conv_blocks = (NN * 32 + 255) / 256;
        conv_h_kernel<true><<<conv_blocks, 256, 0, stream>>>(hA, rowp, edge, hB);
        conv_h_kernel<true><<<conv_blocks, 256, 0, stream>>>(hB, rowp, edge, hA);
        conv_h_kernel<false><<<conv_blocks, 256, 0, stream>>>(hA, rowp, edge, out);
    } else {
        // fallback: atomic fp32 implementation
        float* dinv = (float*)(ws + 1024);
        float* y    = (float*)(ws + 262144);

        hipMemsetAsync(dinv, 0, NN * sizeof(float), stream);
        hipMemsetAsync(out, 0, feat_bytes, stream);
        hipMemsetAsync(y, 0, feat_bytes, stream);

        init_kernel<<<1, 256, 0, stream>>>((const unsigned int*)ei, flag, (int*)(ws + 512), 256);
        deg_kernel<<<(E + 255) / 256, 256, 0, stream>>>(ei, flag, dinv, E);
        dinv_kernel<<<(NN + 255) / 256, 256, 0, stream>>>(dinv);

        const int conv_blocks = (int)(((size_t)E * 32 + 255) / 256);
        conv_atomic_kernel<false><<<conv_blocks, 256, 0, stream>>>(x, ei, flag, dinv, out, E);
        conv_atomic_kernel<true><<<conv_blocks, 256, 0, stream>>>(out, ei, flag, dinv, y, E);
        hipMemsetAsync(out, 0, feat_bytes, stream);
        conv_atomic_kernel<true><<<conv_blocks, 256, 0, stream>>>(y, ei, flag, dinv, out, E);
        relu_kernel<<<(out_size / 4 + 255) / 256, 256, 0, stream>>>((float4*)out, out_size / 4);
    }
}

// Round 10
// 153.408 us; speedup vs baseline: 1.0094x; 1.0094x over previous
//
#include <hip/hip_runtime.h>
#include <hip/hip_fp16.h>

#define NN 50000
#define FEAT 128
#define CSTRIDE 16   // cursor padding: one cursor per 64B line

// Zero hist (grid-wide) + detect int64-vs-int32 edge storage (block 0).
__global__ void init_kernel(const unsigned int* ei32, int* flag, int* hist, int n) {
    int i = blockIdx.x * 256 + threadIdx.x;
    if (i < n) hist[i] = 0;
    if (blockIdx.x == 0) {
        __shared__ int ok;
        if (threadIdx.x == 0) ok = 1;
        __syncthreads();
        if (ei32[2 * threadIdx.x + 1] != 0u) ok = 0;   // benign race: all writers write 0
        __syncthreads();
        if (threadIdx.x == 0) *flag = ok;
    }
}

static __device__ __forceinline__ void load_edge(const void* ei, int is64, int E, int e,
                                                 int& src, int& dst) {
    if (is64) {
        const long long* p = (const long long*)ei;
        src = (int)p[e];
        dst = (int)p[E + e];
    } else {
        const int* p = (const int*)ei;
        src = p[e];
        dst = p[E + e];
    }
}

// ---------------- CSR build ----------------
__global__ void hist_kernel(const void* ei, const int* flag, int* hist, int E) {
    int base = (blockIdx.x * blockDim.x + threadIdx.x) * 4;
    if (base >= E) return;
    const int is64 = *flag;
    int n = E - base; if (n > 4) n = 4;
    int src[4], dst[4];
    #pragma unroll
    for (int i = 0; i < 4; ++i)
        if (i < n) load_edge(ei, is64, E, base + i, src[i], dst[i]);
    #pragma unroll
    for (int i = 0; i < 4; ++i)
        if (i < n) atomicAdd(&hist[dst[i]], 1);
}

// phase 1: per-block (256) scan -> local excl offsets + block sums + dinv (fused)
__global__ void scan_local_kernel(const int* __restrict__ hist, int* __restrict__ local_excl,
                                  int* __restrict__ bsum, float* __restrict__ dinv, int n) {
    __shared__ int sdata[256];
    int i = blockIdx.x * 256 + threadIdx.x;
    int v = (i < n) ? hist[i] : 0;
    if (i < n) dinv[i] = (v > 0) ? rsqrtf((float)v) : 0.0f;
    sdata[threadIdx.x] = v;
    __syncthreads();
    for (int d = 1; d < 256; d <<= 1) {
        int t = (threadIdx.x >= (unsigned)d) ? sdata[threadIdx.x - d] : 0;
        __syncthreads();
        sdata[threadIdx.x] += t;
        __syncthreads();
    }
    if (i < n) local_excl[i] = sdata[threadIdx.x] - v;
    if (threadIdx.x == 255) bsum[blockIdx.x] = sdata[255];
}

// phase 2: single-block exclusive scan of block sums (nb <= 1024)
__global__ void scan_bsum_kernel(int* bsum, int nb) {
    __shared__ int sdata[1024];
    int v = ((int)threadIdx.x < nb) ? bsum[threadIdx.x] : 0;
    sdata[threadIdx.x] = v;
    __syncthreads();
    for (int d = 1; d < 1024; d <<= 1) {
        int t = (threadIdx.x >= (unsigned)d) ? sdata[threadIdx.x - d] : 0;
        __syncthreads();
        sdata[threadIdx.x] += t;
        __syncthreads();
    }
    if ((int)threadIdx.x < nb) bsum[threadIdx.x] = sdata[threadIdx.x] - v;
}

// phase 3: add block offsets -> row_ptr + padded cursor; thread 0 writes row_ptr[n]=E
__global__ void scan_add_kernel(const int* __restrict__ local_excl, const int* __restrict__ bsum,
                                int* __restrict__ rowp, int* __restrict__ curs, int n, int E) {
    int i = blockIdx.x * 256 + threadIdx.x;
    if (i < n) {
        int r = local_excl[i] + bsum[i >> 8];
        rowp[i] = r;
        curs[i * CSTRIDE] = r;      // one cursor per 64B line
    }
    if (i == 0) rowp[n] = E;
}

// scatter {src, weight} packed 8B; padded cursors to kill same-line atomic contention
__global__ void scatter_kernel(const void* ei, const int* flag, int* cursor,
                               unsigned long long* __restrict__ edge,
                               const float* __restrict__ dinv, int E) {
    int base = (blockIdx.x * blockDim.x + threadIdx.x) * 4;
    if (base >= E) return;
    const int is64 = *flag;
    int n = E - base; if (n > 4) n = 4;

    int src[4], dst[4];
    #pragma unroll
    for (int i = 0; i < 4; ++i)
        if (i < n) load_edge(ei, is64, E, base + i, src[i], dst[i]);

    float ds[4], dd[4];
    #pragma unroll
    for (int i = 0; i < 4; ++i)
        if (i < n) { ds[i] = dinv[src[i]]; dd[i] = dinv[dst[i]]; }

    int pos[4];
    #pragma unroll
    for (int i = 0; i < 4; ++i)
        if (i < n) pos[i] = atomicAdd(&cursor[dst[i] * CSTRIDE], 1);

    #pragma unroll
    for (int i = 0; i < 4; ++i)
        if (i < n) {
            float w = ds[i] * dd[i];
            edge[pos[i]] = (unsigned long long)(unsigned int)src[i] |
                           ((unsigned long long)(unsigned int)__float_as_int(w) << 32);
        }
}

static __device__ __forceinline__ float4 relu4(float4 v) {
    v.x = fmaxf(v.x, 0.0f); v.y = fmaxf(v.y, 0.0f);
    v.z = fmaxf(v.z, 0.0f); v.w = fmaxf(v.w, 0.0f);
    return v;
}

static __device__ __forceinline__ void fma4(float4& a, float w, float4 v) {
    a.x += w * v.x; a.y += w * v.y; a.z += w * v.z; a.w += w * v.w;
}

static __device__ __forceinline__ float4 h4_to_f4(uint2 r) {
    __half2 lo = *reinterpret_cast<__half2*>(&r.x);
    __half2 hi = *reinterpret_cast<__half2*>(&r.y);
    float2 f0 = __half22float2(lo);
    float2 f1 = __half22float2(hi);
    return make_float4(f0.x, f0.y, f1.x, f1.y);
}

static __device__ __forceinline__ uint2 f4_to_h4(float4 v) {
    __half2 lo = __floats2half2_rn(v.x, v.y);
    __half2 hi = __floats2half2_rn(v.z, v.w);
    uint2 r;
    r.x = *reinterpret_cast<unsigned int*>(&lo);
    r.y = *reinterpret_cast<unsigned int*>(&hi);
    return r;
}

// convert fp32 features -> fp16 rows
__global__ void cvt_f2h_kernel(const float4* __restrict__ in, uint2* __restrict__ outh, int n4) {
    int i = blockIdx.x * blockDim.x + threadIdx.x;
    if (i >= n4) return;
    outh[i] = f4_to_h4(in[i]);
}

// ---------------- CSR conv (fp16 gather, fp32 accum, ReLU fused into store) ----------------
template <bool OUT_HALF>
__global__ void conv_h_kernel(const uint2* __restrict__ xh,
                              const int* __restrict__ row_ptr,
                              const unsigned long long* __restrict__ edge,
                              void* __restrict__ outbuf) {
    int gid = blockIdx.x * blockDim.x + threadIdx.x;
    int node = gid >> 5;
    int f4   = gid & 31;
    if (node >= NN) return;
    int beg = row_ptr[node];
    int end = row_ptr[node + 1];

    float4 a0 = make_float4(0.f, 0.f, 0.f, 0.f);
    float4 a1 = a0, a2 = a0, a3 = a0;

    for (int cb = beg; cb < end; cb += 32) {
        int rem = end - cb;
        if (rem > 32) rem = 32;
        int myi = (f4 < rem) ? f4 : 0;
        unsigned long long pk = edge[cb + myi];   // one coalesced 8B load / lane

        for (int j = 0; j < rem; j += 8) {
            int i0 = j + 0, i1 = j + 1, i2 = j + 2, i3 = j + 3;
            int i4 = j + 4, i5 = j + 5, i6 = j + 6, i7 = j + 7;
            int last = rem - 1;
            unsigned long long l0 = __shfl(pk, i0 < rem ? i0 : last, 32);
            unsigned long long l1 = __shfl(pk, i1 < rem ? i1 : last, 32);
            unsigned long long l2 = __shfl(pk, i2 < rem ? i2 : last, 32);
            unsigned long long l3 = __shfl(pk, i3 < rem ? i3 : last, 32);
            unsigned long long l4 = __shfl(pk, i4 < rem ? i4 : last, 32);
            unsigned long long l5 = __shfl(pk, i5 < rem ? i5 : last, 32);
            unsigned long long l6 = __shfl(pk, i6 < rem ? i6 : last, 32);
            unsigned long long l7 = __shfl(pk, i7 < rem ? i7 : last, 32);

            float w0 = (i0 < rem) ? __int_as_float((int)(l0 >> 32)) : 0.0f;
            float w1 = (i1 < rem) ? __int_as_float((int)(l1 >> 32)) : 0.0f;
            float w2 = (i2 < rem) ? __int_as_float((int)(l2 >> 32)) : 0.0f;
            float w3 = (i3 < rem) ? __int_as_float((int)(l3 >> 32)) : 0.0f;
            float w4 = (i4 < rem) ? __int_as_float((int)(l4 >> 32)) : 0.0f;
            float w5 = (i5 < rem) ? __int_as_float((int)(l5 >> 32)) : 0.0f;
            float w6 = (i6 < rem) ? __int_as_float((int)(l6 >> 32)) : 0.0f;
            float w7 = (i7 < rem) ? __int_as_float((int)(l7 >> 32)) : 0.0f;

            uint2 r0 = xh[(int)(unsigned int)l0 * 32 + f4];
            uint2 r1 = xh[(int)(unsigned int)l1 * 32 + f4];
            uint2 r2 = xh[(int)(unsigned int)l2 * 32 + f4];
            uint2 r3 = xh[(int)(unsigned int)l3 * 32 + f4];
            uint2 r4 = xh[(int)(unsigned int)l4 * 32 + f4];
            uint2 r5 = xh[(int)(unsigned int)l5 * 32 + f4];
            uint2 r6 = xh[(int)(unsigned int)l6 * 32 + f4];
            uint2 r7 = xh[(int)(unsigned int)l7 * 32 + f4];

            fma4(a0, w0, h4_to_f4(r0));
            fma4(a1, w1, h4_to_f4(r1));
            fma4(a2, w2, h4_to_f4(r2));
            fma4(a3, w3, h4_to_f4(r3));
            fma4(a0, w4, h4_to_f4(r4));
            fma4(a1, w5, h4_to_f4(r5));
            fma4(a2, w6, h4_to_f4(r6));
            fma4(a3, w7, h4_to_f4(r7));
        }
    }

    float4 acc;
    acc.x = (a0.x + a1.x) + (a2.x + a3.x);
    acc.y = (a0.y + a1.y) + (a2.y + a3.y);
    acc.z = (a0.z + a1.z) + (a2.z + a3.z);
    acc.w = (a0.w + a1.w) + (a2.w + a3.w);
    acc = relu4(acc);   // every layer output is ReLU'd

    if (OUT_HALF) {
        ((uint2*)outbuf)[node * 32 + f4] = f4_to_h4(acc);
    } else {
        ((float4*)outbuf)[node * 32 + f4] = acc;
    }
}

// ---------------- fallback (atomic) path kernels ----------------
__global__ void deg_kernel(const void* ei, const int* flag, float* deg, int E) {
    int e = blockIdx.x * blockDim.x + threadIdx.x;
    if (e >= E) return;
    int src, dst;
    load_edge(ei, *flag, E, e, src, dst);
    atomicAdd(&deg[dst], 1.0f);
}

__global__ void dinv_kernel(float* deg) {
    int i = blockIdx.x * blockDim.x + threadIdx.x;
    if (i >= NN) return;
    float d = deg[i];
    deg[i] = (d > 0.0f) ? (1.0f / sqrtf(d)) : 0.0f;
}

template <bool RELU_IN>
__global__ void conv_atomic_kernel(const float* __restrict__ xin, const void* ei, const int* flag,
                                   const float* __restrict__ dinv, float* __restrict__ yout, int E) {
    int gid = blockIdx.x * blockDim.x + threadIdx.x;
    int e  = gid >> 5;
    int f4 = gid & 31;
    if (e >= E) return;
    int src, dst;
    load_edge(ei, *flag, E, e, src, dst);
    float w = dinv[src] * dinv[dst];
    float4 v = ((const float4*)xin)[src * 32 + f4];
    if (RELU_IN) v = relu4(v);
    float* o = yout + (size_t)dst * FEAT + f4 * 4;
    atomicAdd(o + 0, v.x * w);
    atomicAdd(o + 1, v.y * w);
    atomicAdd(o + 2, v.z * w);
    atomicAdd(o + 3, v.w * w);
}

__global__ void relu_kernel(float4* buf, int n4) {
    int i = blockIdx.x * blockDim.x + threadIdx.x;
    if (i >= n4) return;
    buf[i] = relu4(buf[i]);
}

extern "C" void kernel_launch(void* const* d_in, const int* in_sizes, int n_in,
                              void* d_out, int out_size, void* d_ws, size_t ws_size,
                              hipStream_t stream) {
    const float* x  = (const float*)d_in[0];
    const void*  ei = d_in[1];
    const int E = in_sizes[1] / 2;

    float* out = (float*)d_out;
    char*  ws  = (char*)d_ws;

    const size_t feat_bytes  = (size_t)NN * FEAT * sizeof(float);
    const size_t half_bytes  = (size_t)NN * FEAT * sizeof(unsigned short);
    const int NB = (NN + 255) / 256;
    const int N4 = NN * 32;

    // ws layout (CSR fp16 path)
    const size_t OFF_FLAG = 0;
    const size_t OFF_HIST = 1024;
    const size_t OFF_DINV = OFF_HIST + (((size_t)NN * 4 + 255) & ~255ull);
    const size_t OFF_ROWP = OFF_DINV + (((size_t)NN * 4 + 255) & ~255ull);
    const size_t OFF_CURS = OFF_ROWP + ((((size_t)NN + 1) * 4 + 255) & ~255ull);
    const size_t OFF_BSUM = OFF_CURS + (((size_t)NN * 4 * CSTRIDE + 255) & ~255ull);
    const size_t OFF_EDG  = OFF_BSUM + ((1024 * 4 + 255) & ~255ull);
    const size_t OFF_HA   = OFF_EDG + (((size_t)E * 8 + 255) & ~255ull);
    const size_t OFF_HB   = OFF_HA + ((half_bytes + 255) & ~255ull);
    const size_t NEEDED   = OFF_HB + half_bytes;

    int* flag = (int*)(ws + OFF_FLAG);

    if (ws_size >= NEEDED) {
        int*   hist = (int*)(ws + OFF_HIST);
        float* dinv = (float*)(ws + OFF_DINV);
        int*   rowp = (int*)(ws + OFF_ROWP);
        int*   curs = (int*)(ws + OFF_CURS);
        int*   bsum = (int*)(ws + OFF_BSUM);
        unsigned long long* edge = (unsigned long long*)(ws + OFF_EDG);
        uint2* hA   = (uint2*)(ws + OFF_HA);
        uint2* hB   = (uint2*)(ws + OFF_HB);

        init_kernel<<<NB, 256, 0, stream>>>((const unsigned int*)ei, flag, hist, NN);

        const int e4_blocks = (E / 4 + 255) / 256 + 1;
        hist_kernel<<<e4_blocks, 256, 0, stream>>>(ei, flag, hist, E);
        scan_local_kernel<<<NB, 256, 0, stream>>>(hist, rowp, bsum, dinv, NN);
        scan_bsum_kernel<<<1, 1024, 0, stream>>>(bsum, NB);
        scan_add_kernel<<<NB, 256, 0, stream>>>(rowp, bsum, rowp, curs, NN, E);
        scatter_kernel<<<e4_blocks, 256, 0, stream>>>(ei, flag, curs, edge, dinv, E);

        cvt_f2h_kernel<<<(N4 + 255) / 256, 256, 0, stream>>>((const float4*)x, hA, N4);

        const int conv_blocks = (NN * 32 + 255) / 256;
        conv_h_kernel<true><<<conv_blocks, 256, 0, stream>>>(hA, rowp, edge, hB);
        conv_h_kernel<true><<<conv_blocks, 256, 0, stream>>>(hB, rowp, edge, hA);
        conv_h_kernel<false><<<conv_blocks, 256, 0, stream>>>(hA, rowp, edge, out);
    } else {
        // fallback: atomic fp32 implementation
        float* dinv = (float*)(ws + 1024);
        float* y    = (float*)(ws + 262144);

        hipMemsetAsync(dinv, 0, NN * sizeof(float), stream);
        hipMemsetAsync(out, 0, feat_bytes, stream);
        hipMemsetAsync(y, 0, feat_bytes, stream);

        init_kernel<<<1, 256, 0, stream>>>((const unsigned int*)ei, flag, (int*)(ws + 512), 256);
        deg_kernel<<<(E + 255) / 256, 256, 0, stream>>>(ei, flag, dinv, E);
        dinv_kernel<<<(NN + 255) / 256, 256, 0, stream>>>(dinv);

        const int conv_blocks = (int)(((size_t)E * 32 + 255) / 256);
        conv_atomic_kernel<false><<<conv_blocks, 256, 0, stream>>>(x, ei, flag, dinv, out, E);
        conv_atomic_kernel<true><<<conv_blocks, 256, 0, stream>>>(out, ei, flag, dinv, y, E);
        hipMemsetAsync(out, 0, feat_bytes, stream);
        conv_atomic_kernel<true><<<conv_blocks, 256, 0, stream>>>(y, ei, flag, dinv, out, E);
        relu_kernel<<<(out_size / 4 + 255) / 256, 256, 0, stream>>>((float4*)out, out_size / 4);
    }
}

// Round 11
// 149.524 us; speedup vs baseline: 1.0356x; 1.0260x over previous
//
#include <hip/hip_runtime.h>
#include <hip/hip_fp16.h>

#define NN 50000
#define FEAT 128
#define CSTRIDE 16   // cursor padding: one cursor per 64B line

// Zero hist (grid-wide) + detect int64-vs-int32 edge storage (block 0).
__global__ void init_kernel(const unsigned int* ei32, int* flag, int* hist, int n) {
    int i = blockIdx.x * 256 + threadIdx.x;
    if (i < n) hist[i] = 0;
    if (blockIdx.x == 0) {
        __shared__ int ok;
        if (threadIdx.x == 0) ok = 1;
        __syncthreads();
        if (ei32[2 * threadIdx.x + 1] != 0u) ok = 0;   // benign race: all writers write 0
        __syncthreads();
        if (threadIdx.x == 0) *flag = ok;
    }
}

static __device__ __forceinline__ void load_edge(const void* ei, int is64, int E, int e,
                                                 int& src, int& dst) {
    if (is64) {
        const long long* p = (const long long*)ei;
        src = (int)p[e];
        dst = (int)p[E + e];
    } else {
        const int* p = (const int*)ei;
        src = p[e];
        dst = p[E + e];
    }
}

// ---------------- CSR build ----------------
__global__ void hist_kernel(const void* ei, const int* flag, int* hist, int E) {
    int base = (blockIdx.x * blockDim.x + threadIdx.x) * 4;
    if (base >= E) return;
    const int is64 = *flag;
    int n = E - base; if (n > 4) n = 4;
    int src[4], dst[4];
    #pragma unroll
    for (int i = 0; i < 4; ++i)
        if (i < n) load_edge(ei, is64, E, base + i, src[i], dst[i]);
    #pragma unroll
    for (int i = 0; i < 4; ++i)
        if (i < n) atomicAdd(&hist[dst[i]], 1);
}

// phase 1: per-block (256) scan -> local excl offsets + block sums + dinv (fused)
__global__ void scan_local_kernel(const int* __restrict__ hist, int* __restrict__ local_excl,
                                  int* __restrict__ bsum, float* __restrict__ dinv, int n) {
    __shared__ int sdata[256];
    int i = blockIdx.x * 256 + threadIdx.x;
    int v = (i < n) ? hist[i] : 0;
    if (i < n) dinv[i] = (v > 0) ? rsqrtf((float)v) : 0.0f;
    sdata[threadIdx.x] = v;
    __syncthreads();
    for (int d = 1; d < 256; d <<= 1) {
        int t = (threadIdx.x >= (unsigned)d) ? sdata[threadIdx.x - d] : 0;
        __syncthreads();
        sdata[threadIdx.x] += t;
        __syncthreads();
    }
    if (i < n) local_excl[i] = sdata[threadIdx.x] - v;
    if (threadIdx.x == 255) bsum[blockIdx.x] = sdata[255];
}

// phase 2: single-block exclusive scan of block sums (nb <= 1024)
__global__ void scan_bsum_kernel(int* bsum, int nb) {
    __shared__ int sdata[1024];
    int v = ((int)threadIdx.x < nb) ? bsum[threadIdx.x] : 0;
    sdata[threadIdx.x] = v;
    __syncthreads();
    for (int d = 1; d < 1024; d <<= 1) {
        int t = (threadIdx.x >= (unsigned)d) ? sdata[threadIdx.x - d] : 0;
        __syncthreads();
        sdata[threadIdx.x] += t;
        __syncthreads();
    }
    if ((int)threadIdx.x < nb) bsum[threadIdx.x] = sdata[threadIdx.x] - v;
}

// phase 3: add block offsets -> row_ptr + padded cursor; thread 0 writes row_ptr[n]=E
__global__ void scan_add_kernel(const int* __restrict__ local_excl, const int* __restrict__ bsum,
                                int* __restrict__ rowp, int* __restrict__ curs, int n, int E) {
    int i = blockIdx.x * 256 + threadIdx.x;
    if (i < n) {
        int r = local_excl[i] + bsum[i >> 8];
        rowp[i] = r;
        curs[i * CSTRIDE] = r;
    }
    if (i == 0) rowp[n] = E;
}

// scatter col only (4B): weights are factored into per-node scalars now
__global__ void scatter_kernel(const void* ei, const int* flag, int* cursor,
                               int* __restrict__ col, int E) {
    int base = (blockIdx.x * blockDim.x + threadIdx.x) * 4;
    if (base >= E) return;
    const int is64 = *flag;
    int n = E - base; if (n > 4) n = 4;

    int src[4], dst[4];
    #pragma unroll
    for (int i = 0; i < 4; ++i)
        if (i < n) load_edge(ei, is64, E, base + i, src[i], dst[i]);

    int pos[4];
    #pragma unroll
    for (int i = 0; i < 4; ++i)
        if (i < n) pos[i] = atomicAdd(&cursor[dst[i] * CSTRIDE], 1);

    #pragma unroll
    for (int i = 0; i < 4; ++i)
        if (i < n) col[pos[i]] = src[i];
}

static __device__ __forceinline__ float4 relu4(float4 v) {
    v.x = fmaxf(v.x, 0.0f); v.y = fmaxf(v.y, 0.0f);
    v.z = fmaxf(v.z, 0.0f); v.w = fmaxf(v.w, 0.0f);
    return v;
}

static __device__ __forceinline__ void fma4(float4& a, float w, float4 v) {
    a.x += w * v.x; a.y += w * v.y; a.z += w * v.z; a.w += w * v.w;
}

static __device__ __forceinline__ float4 h4_to_f4(uint2 r) {
    __half2 lo = *reinterpret_cast<__half2*>(&r.x);
    __half2 hi = *reinterpret_cast<__half2*>(&r.y);
    float2 f0 = __half22float2(lo);
    float2 f1 = __half22float2(hi);
    return make_float4(f0.x, f0.y, f1.x, f1.y);
}

static __device__ __forceinline__ uint2 f4_to_h4(float4 v) {
    __half2 lo = __floats2half2_rn(v.x, v.y);
    __half2 hi = __floats2half2_rn(v.z, v.w);
    uint2 r;
    r.x = *reinterpret_cast<unsigned int*>(&lo);
    r.y = *reinterpret_cast<unsigned int*>(&hi);
    return r;
}

// convert fp32 features -> fp16 rows PRE-SCALED by dinv[node]
__global__ void cvt_f2h_kernel(const float4* __restrict__ in, const float* __restrict__ dinv,
                               uint2* __restrict__ outh, int n4) {
    int i = blockIdx.x * blockDim.x + threadIdx.x;
    if (i >= n4) return;
    float dd = dinv[i >> 5];
    float4 v = in[i];
    v.x *= dd; v.y *= dd; v.z *= dd; v.w *= dd;
    outh[i] = f4_to_h4(v);
}

// ---------------- CSR conv ----------------
// xh rows are pre-scaled by dinv[src]; accumulate raw sums, then per-node:
//   out      = relu(dinv[node] * acc)
//   OUT_HALF: store fp16( dinv[node] * out )  (pre-scaled for next layer)
//   else:     store fp32( out )               (final layer)
template <bool OUT_HALF>
__global__ void conv_h_kernel(const uint2* __restrict__ xh,
                              const int* __restrict__ row_ptr,
                              const int* __restrict__ col,
                              const float* __restrict__ dinv,
                              void* __restrict__ outbuf) {
    int gid = blockIdx.x * blockDim.x + threadIdx.x;
    int node = gid >> 5;
    int f4   = gid & 31;
    if (node >= NN) return;
    int beg = row_ptr[node];
    int end = row_ptr[node + 1];
    float dd = dinv[node];

    float4 a0 = make_float4(0.f, 0.f, 0.f, 0.f);
    float4 a1 = a0, a2 = a0, a3 = a0;

    for (int cb = beg; cb < end; cb += 32) {
        int rem = end - cb;
        if (rem > 32) rem = 32;
        int myi = (f4 < rem) ? f4 : 0;
        int pk = col[cb + myi];   // one coalesced 4B load / lane covers 32 edges

        for (int j = 0; j < rem; j += 8) {
            int i0 = j + 0, i1 = j + 1, i2 = j + 2, i3 = j + 3;
            int i4 = j + 4, i5 = j + 5, i6 = j + 6, i7 = j + 7;
            int last = rem - 1;
            int c0 = __shfl(pk, i0 < rem ? i0 : last, 32);
            int c1 = __shfl(pk, i1 < rem ? i1 : last, 32);
            int c2 = __shfl(pk, i2 < rem ? i2 : last, 32);
            int c3 = __shfl(pk, i3 < rem ? i3 : last, 32);
            int c4 = __shfl(pk, i4 < rem ? i4 : last, 32);
            int c5 = __shfl(pk, i5 < rem ? i5 : last, 32);
            int c6 = __shfl(pk, i6 < rem ? i6 : last, 32);
            int c7 = __shfl(pk, i7 < rem ? i7 : last, 32);

            float w0 = (i0 < rem) ? 1.0f : 0.0f;
            float w1 = (i1 < rem) ? 1.0f : 0.0f;
            float w2 = (i2 < rem) ? 1.0f : 0.0f;
            float w3 = (i3 < rem) ? 1.0f : 0.0f;
            float w4 = (i4 < rem) ? 1.0f : 0.0f;
            float w5 = (i5 < rem) ? 1.0f : 0.0f;
            float w6 = (i6 < rem) ? 1.0f : 0.0f;
            float w7 = (i7 < rem) ? 1.0f : 0.0f;

            uint2 r0 = xh[c0 * 32 + f4];
            uint2 r1 = xh[c1 * 32 + f4];
            uint2 r2 = xh[c2 * 32 + f4];
            uint2 r3 = xh[c3 * 32 + f4];
            uint2 r4 = xh[c4 * 32 + f4];
            uint2 r5 = xh[c5 * 32 + f4];
            uint2 r6 = xh[c6 * 32 + f4];
            uint2 r7 = xh[c7 * 32 + f4];

            fma4(a0, w0, h4_to_f4(r0));
            fma4(a1, w1, h4_to_f4(r1));
            fma4(a2, w2, h4_to_f4(r2));
            fma4(a3, w3, h4_to_f4(r3));
            fma4(a0, w4, h4_to_f4(r4));
            fma4(a1, w5, h4_to_f4(r5));
            fma4(a2, w6, h4_to_f4(r6));
            fma4(a3, w7, h4_to_f4(r7));
        }
    }

    float4 acc;
    acc.x = (a0.x + a1.x) + (a2.x + a3.x);
    acc.y = (a0.y + a1.y) + (a2.y + a3.y);
    acc.z = (a0.z + a1.z) + (a2.z + a3.z);
    acc.w = (a0.w + a1.w) + (a2.w + a3.w);
    // out = relu(dd * acc)
    acc.x *= dd; acc.y *= dd; acc.z *= dd; acc.w *= dd;
    acc = relu4(acc);

    if (OUT_HALF) {
        // pre-scale for next layer: store dd * out
        acc.x *= dd; acc.y *= dd; acc.z *= dd; acc.w *= dd;
        ((uint2*)outbuf)[node * 32 + f4] = f4_to_h4(acc);
    } else {
        ((float4*)outbuf)[node * 32 + f4] = acc;
    }
}

// ---------------- fallback (atomic) path kernels ----------------
__global__ void deg_kernel(const void* ei, const int* flag, float* deg, int E) {
    int e = blockIdx.x * blockDim.x + threadIdx.x;
    if (e >= E) return;
    int src, dst;
    load_edge(ei, *flag, E, e, src, dst);
    atomicAdd(&deg[dst], 1.0f);
}

__global__ void dinv_kernel(float* deg) {
    int i = blockIdx.x * blockDim.x + threadIdx.x;
    if (i >= NN) return;
    float d = deg[i];
    deg[i] = (d > 0.0f) ? (1.0f / sqrtf(d)) : 0.0f;
}

template <bool RELU_IN>
__global__ void conv_atomic_kernel(const float* __restrict__ xin, const void* ei, const int* flag,
                                   const float* __restrict__ dinv, float* __restrict__ yout, int E) {
    int gid = blockIdx.x * blockDim.x + threadIdx.x;
    int e  = gid >> 5;
    int f4 = gid & 31;
    if (e >= E) return;
    int src, dst;
    load_edge(ei, *flag, E, e, src, dst);
    float w = dinv[src] * dinv[dst];
    float4 v = ((const float4*)xin)[src * 32 + f4];
    if (RELU_IN) v = relu4(v);
    float* o = yout + (size_t)dst * FEAT + f4 * 4;
    atomicAdd(o + 0, v.x * w);
    atomicAdd(o + 1, v.y * w);
    atomicAdd(o + 2, v.z * w);
    atomicAdd(o + 3, v.w * w);
}

__global__ void relu_kernel(float4* buf, int n4) {
    int i = blockIdx.x * blockDim.x + threadIdx.x;
    if (i >= n4) return;
    buf[i] = relu4(buf[i]);
}

extern "C" void kernel_launch(void* const* d_in, const int* in_sizes, int n_in,
                              void* d_out, int out_size, void* d_ws, size_t ws_size,
                              hipStream_t stream) {
    const float* x  = (const float*)d_in[0];
    const void*  ei = d_in[1];
    const int E = in_sizes[1] / 2;

    float* out = (float*)d_out;
    char*  ws  = (char*)d_ws;

    const size_t feat_bytes  = (size_t)NN * FEAT * sizeof(float);
    const size_t half_bytes  = (size_t)NN * FEAT * sizeof(unsigned short);
    const int NB = (NN + 255) / 256;
    const int N4 = NN * 32;

    // ws layout (CSR fp16 path)
    const size_t OFF_FLAG = 0;
    const size_t OFF_HIST = 1024;
    const size_t OFF_DINV = OFF_HIST + (((size_t)NN * 4 + 255) & ~255ull);
    const size_t OFF_ROWP = OFF_DINV + (((size_t)NN * 4 + 255) & ~255ull);
    const size_t OFF_CURS = OFF_ROWP + ((((size_t)NN + 1) * 4 + 255) & ~255ull);
    const size_t OFF_BSUM = OFF_CURS + (((size_t)NN * 4 * CSTRIDE + 255) & ~255ull);
    const size_t OFF_EDG  = OFF_BSUM + ((1024 * 4 + 255) & ~255ull);
    const size_t OFF_HA   = OFF_EDG + (((size_t)E * 4 + 255) & ~255ull);
    const size_t OFF_HB   = OFF_HA + ((half_bytes + 255) & ~255ull);
    const size_t NEEDED   = OFF_HB + half_bytes;

    int* flag = (int*)(ws + OFF_FLAG);

    if (ws_size >= NEEDED) {
        int*   hist = (int*)(ws + OFF_HIST);
        float* dinv = (float*)(ws + OFF_DINV);
        int*   rowp = (int*)(ws + OFF_ROWP);
        int*   curs = (int*)(ws + OFF_CURS);
        int*   bsum = (int*)(ws + OFF_BSUM);
        int*   col  = (int*)(ws + OFF_EDG);
        uint2* hA   = (uint2*)(ws + OFF_HA);
        uint2* hB   = (uint2*)(ws + OFF_HB);

        init_kernel<<<NB, 256, 0, stream>>>((const unsigned int*)ei, flag, hist, NN);

        const int e4_blocks = (E / 4 + 255) / 256 + 1;
        hist_kernel<<<e4_blocks, 256, 0, stream>>>(ei, flag, hist, E);
        scan_local_kernel<<<NB, 256, 0, stream>>>(hist, rowp, bsum, dinv, NN);
        // cvt needs dinv (ready after scan_local); also overlaps the scan tail
        cvt_f2h_kernel<<<(N4 + 255) / 256, 256, 0, stream>>>((const float4*)x, dinv, hA, N4);
        scan_bsum_kernel<<<1, 1024, 0, stream>>>(bsum, NB);
        scan_add_kernel<<<NB, 256, 0, stream>>>(rowp, bsum, rowp, curs, NN, E);
        scatter_kernel<<<e4_blocks, 256, 0, stream>>>(ei, flag, curs, col, E);

        const int conv_blocks = (NN * 32 + 255) / 256;
        conv_h_kernel<true><<<conv_blocks, 256, 0, stream>>>(hA, rowp, col, dinv, hB);
        conv_h_kernel<true><<<conv_blocks, 256, 0, stream>>>(hB, rowp, col, dinv, hA);
        conv_h_kernel<false><<<conv_blocks, 256, 0, stream>>>(hA, rowp, col, dinv, out);
    } else {
        // fallback: atomic fp32 implementation
        float* dinv = (float*)(ws + 1024);
        float* y    = (float*)(ws + 262144);

        hipMemsetAsync(dinv, 0, NN * sizeof(float), stream);
        hipMemsetAsync(out, 0, feat_bytes, stream);
        hipMemsetAsync(y, 0, feat_bytes, stream);

        init_kernel<<<1, 256, 0, stream>>>((const unsigned int*)ei, flag, (int*)(ws + 512), 256);
        deg_kernel<<<(E + 255) / 256, 256, 0, stream>>>(ei, flag, dinv, E);
        dinv_kernel<<<(NN + 255) / 256, 256, 0, stream>>>(dinv);

        const int conv_blocks = (int)(((size_t)E * 32 + 255) / 256);
        conv_atomic_kernel<false><<<conv_blocks, 256, 0, stream>>>(x, ei, flag, dinv, out, E);
        conv_atomic_kernel<true><<<conv_blocks, 256, 0, stream>>>(out, ei, flag, dinv, y, E);
        hipMemsetAsync(out, 0, feat_bytes, stream);
        conv_atomic_kernel<true><<<conv_blocks, 256, 0, stream>>>(y, ei, flag, dinv, out, E);
        relu_kernel<<<(out_size / 4 + 255) / 256, 256, 0, stream>>>((float4*)out, out_size / 4);
    }
}

// Round 13
// 144.687 us; speedup vs baseline: 1.0703x; 1.0334x over previous
//
#include <hip/hip_runtime.h>
#include <hip/hip_fp16.h>

#define NN 50000
#define FEAT 128

// Zero hist (grid-wide) + detect int64-vs-int32 edge storage (block 0).
__global__ void init_kernel(const unsigned int* ei32, int* flag, int* hist, int n) {
    int i = blockIdx.x * 256 + threadIdx.x;
    if (i < n) hist[i] = 0;
    if (blockIdx.x == 0) {
        __shared__ int ok;
        if (threadIdx.x == 0) ok = 1;
        __syncthreads();
        if (ei32[2 * threadIdx.x + 1] != 0u) ok = 0;   // benign race: all writers write 0
        __syncthreads();
        if (threadIdx.x == 0) *flag = ok;
    }
}

static __device__ __forceinline__ void load_edge(const void* ei, int is64, int E, int e,
                                                 int& src, int& dst) {
    if (is64) {
        const long long* p = (const long long*)ei;
        src = (int)p[e];
        dst = (int)p[E + e];
    } else {
        const int* p = (const int*)ei;
        src = p[e];
        dst = p[E + e];
    }
}

// ---------------- CSR build ----------------
// pass 1: per-dst rank via returning atomic; rank stored COALESCED.
// hist ends up holding the degree of every node.
__global__ void rank_kernel(const void* ei, const int* flag, int* hist,
                            int* __restrict__ rank, int E) {
    int base = (blockIdx.x * blockDim.x + threadIdx.x) * 4;
    if (base >= E) return;
    const int is64 = *flag;
    int n = E - base; if (n > 4) n = 4;
    int src[4], dst[4];
    #pragma unroll
    for (int i = 0; i < 4; ++i)
        if (i < n) load_edge(ei, is64, E, base + i, src[i], dst[i]);
    int r[4];
    #pragma unroll
    for (int i = 0; i < 4; ++i)
        if (i < n) r[i] = atomicAdd(&hist[dst[i]], 1);
    #pragma unroll
    for (int i = 0; i < 4; ++i)
        if (i < n) rank[base + i] = r[i];
}

// phase 1: per-block (256) scan -> local excl offsets + block sums + dinv (fused)
__global__ void scan_local_kernel(const int* __restrict__ hist, int* __restrict__ local_excl,
                                  int* __restrict__ bsum, float* __restrict__ dinv, int n) {
    __shared__ int sdata[256];
    int i = blockIdx.x * 256 + threadIdx.x;
    int v = (i < n) ? hist[i] : 0;
    if (i < n) dinv[i] = (v > 0) ? rsqrtf((float)v) : 0.0f;
    sdata[threadIdx.x] = v;
    __syncthreads();
    for (int d = 1; d < 256; d <<= 1) {
        int t = (threadIdx.x >= (unsigned)d) ? sdata[threadIdx.x - d] : 0;
        __syncthreads();
        sdata[threadIdx.x] += t;
        __syncthreads();
    }
    if (i < n) local_excl[i] = sdata[threadIdx.x] - v;
    if (threadIdx.x == 255) bsum[blockIdx.x] = sdata[255];
}

// phase 2: single-block exclusive scan of block sums (nb <= 1024)
__global__ void scan_bsum_kernel(int* bsum, int nb) {
    __shared__ int sdata[1024];
    int v = ((int)threadIdx.x < nb) ? bsum[threadIdx.x] : 0;
    sdata[threadIdx.x] = v;
    __syncthreads();
    for (int d = 1; d < 1024; d <<= 1) {
        int t = (threadIdx.x >= (unsigned)d) ? sdata[threadIdx.x - d] : 0;
        __syncthreads();
        sdata[threadIdx.x] += t;
        __syncthreads();
    }
    if ((int)threadIdx.x < nb) bsum[threadIdx.x] = sdata[threadIdx.x] - v;
}

// phase 3: add block offsets -> row_ptr; thread 0 writes row_ptr[n]=E
__global__ void scan_add_kernel(const int* __restrict__ local_excl, const int* __restrict__ bsum,
                                int* __restrict__ rowp, int n, int E) {
    int i = blockIdx.x * 256 + threadIdx.x;
    if (i < n) rowp[i] = local_excl[i] + bsum[i >> 8];
    if (i == 0) rowp[n] = E;
}

// pass 2: placement, NO atomics: col[rowp[dst] + rank[e]] = src  (nontemporal store)
__global__ void place_kernel(const void* ei, const int* flag,
                             const int* __restrict__ rowp, const int* __restrict__ rank,
                             int* __restrict__ col, int E) {
    int base = (blockIdx.x * blockDim.x + threadIdx.x) * 4;
    if (base >= E) return;
    const int is64 = *flag;
    int n = E - base; if (n > 4) n = 4;
    int src[4], dst[4], r[4];
    #pragma unroll
    for (int i = 0; i < 4; ++i)
        if (i < n) { load_edge(ei, is64, E, base + i, src[i], dst[i]); r[i] = rank[base + i]; }
    int rp[4];
    #pragma unroll
    for (int i = 0; i < 4; ++i)
        if (i < n) rp[i] = rowp[dst[i]];
    #pragma unroll
    for (int i = 0; i < 4; ++i)
        if (i < n) __builtin_nontemporal_store(src[i], &col[rp[i] + r[i]]);
}

static __device__ __forceinline__ float4 relu4(float4 v) {
    v.x = fmaxf(v.x, 0.0f); v.y = fmaxf(v.y, 0.0f);
    v.z = fmaxf(v.z, 0.0f); v.w = fmaxf(v.w, 0.0f);
    return v;
}

static __device__ __forceinline__ void fma4(float4& a, float w, float4 v) {
    a.x += w * v.x; a.y += w * v.y; a.z += w * v.z; a.w += w * v.w;
}

static __device__ __forceinline__ float4 h4_to_f4(uint2 r) {
    __half2 lo = *reinterpret_cast<__half2*>(&r.x);
    __half2 hi = *reinterpret_cast<__half2*>(&r.y);
    float2 f0 = __half22float2(lo);
    float2 f1 = __half22float2(hi);
    return make_float4(f0.x, f0.y, f1.x, f1.y);
}

static __device__ __forceinline__ uint2 f4_to_h4(float4 v) {
    __half2 lo = __floats2half2_rn(v.x, v.y);
    __half2 hi = __floats2half2_rn(v.z, v.w);
    uint2 r;
    r.x = *reinterpret_cast<unsigned int*>(&lo);
    r.y = *reinterpret_cast<unsigned int*>(&hi);
    return r;
}

// convert fp32 features -> fp16 rows PRE-SCALED by dinv[node]
__global__ void cvt_f2h_kernel(const float4* __restrict__ in, const float* __restrict__ dinv,
                               uint2* __restrict__ outh, int n4) {
    int i = blockIdx.x * blockDim.x + threadIdx.x;
    if (i >= n4) return;
    float dd = dinv[i >> 5];
    float4 v = in[i];
    v.x *= dd; v.y *= dd; v.z *= dd; v.w *= dd;
    outh[i] = f4_to_h4(v);
}

// ---------------- CSR conv ----------------
// xh rows pre-scaled by dinv[src]; acc raw sums; out = relu(dinv*acc);
// OUT_HALF stores dinv*out (pre-scaled for the next layer), else fp32 out.
template <bool OUT_HALF>
__global__ void conv_h_kernel(const uint2* __restrict__ xh,
                              const int* __restrict__ row_ptr,
                              const int* __restrict__ col,
                              const float* __restrict__ dinv,
                              void* __restrict__ outbuf) {
    int gid = blockIdx.x * blockDim.x + threadIdx.x;
    int node = gid >> 5;
    int f4   = gid & 31;
    if (node >= NN) return;
    int beg = row_ptr[node];
    int end = row_ptr[node + 1];
    float dd = dinv[node];

    float4 a0 = make_float4(0.f, 0.f, 0.f, 0.f);
    float4 a1 = a0, a2 = a0, a3 = a0;

    for (int cb = beg; cb < end; cb += 32) {
        int rem = end - cb;
        if (rem > 32) rem = 32;
        int myi = (f4 < rem) ? f4 : 0;
        int pk = __builtin_nontemporal_load(&col[cb + myi]);  // read-once stream

        for (int j = 0; j < rem; j += 8) {
            int i0 = j + 0, i1 = j + 1, i2 = j + 2, i3 = j + 3;
            int i4 = j + 4, i5 = j + 5, i6 = j + 6, i7 = j + 7;
            int last = rem - 1;
            int c0 = __shfl(pk, i0 < rem ? i0 : last, 32);
            int c1 = __shfl(pk, i1 < rem ? i1 : last, 32);
            int c2 = __shfl(pk, i2 < rem ? i2 : last, 32);
            int c3 = __shfl(pk, i3 < rem ? i3 : last, 32);
            int c4 = __shfl(pk, i4 < rem ? i4 : last, 32);
            int c5 = __shfl(pk, i5 < rem ? i5 : last, 32);
            int c6 = __shfl(pk, i6 < rem ? i6 : last, 32);
            int c7 = __shfl(pk, i7 < rem ? i7 : last, 32);

            float w0 = (i0 < rem) ? 1.0f : 0.0f;
            float w1 = (i1 < rem) ? 1.0f : 0.0f;
            float w2 = (i2 < rem) ? 1.0f : 0.0f;
            float w3 = (i3 < rem) ? 1.0f : 0.0f;
            float w4 = (i4 < rem) ? 1.0f : 0.0f;
            float w5 = (i5 < rem) ? 1.0f : 0.0f;
            float w6 = (i6 < rem) ? 1.0f : 0.0f;
            float w7 = (i7 < rem) ? 1.0f : 0.0f;

            uint2 r0 = xh[c0 * 32 + f4];
            uint2 r1 = xh[c1 * 32 + f4];
            uint2 r2 = xh[c2 * 32 + f4];
            uint2 r3 = xh[c3 * 32 + f4];
            uint2 r4 = xh[c4 * 32 + f4];
            uint2 r5 = xh[c5 * 32 + f4];
            uint2 r6 = xh[c6 * 32 + f4];
            uint2 r7 = xh[c7 * 32 + f4];

            fma4(a0, w0, h4_to_f4(r0));
            fma4(a1, w1, h4_to_f4(r1));
            fma4(a2, w2, h4_to_f4(r2));
            fma4(a3, w3, h4_to_f4(r3));
            fma4(a0, w4, h4_to_f4(r4));
            fma4(a1, w5, h4_to_f4(r5));
            fma4(a2, w6, h4_to_f4(r6));
            fma4(a3, w7, h4_to_f4(r7));
        }
    }

    float4 acc;
    acc.x = (a0.x + a1.x) + (a2.x + a3.x);
    acc.y = (a0.y + a1.y) + (a2.y + a3.y);
    acc.z = (a0.z + a1.z) + (a2.z + a3.z);
    acc.w = (a0.w + a1.w) + (a2.w + a3.w);
    acc.x *= dd; acc.y *= dd; acc.z *= dd; acc.w *= dd;
    acc = relu4(acc);

    if (OUT_HALF) {
        acc.x *= dd; acc.y *= dd; acc.z *= dd; acc.w *= dd;
        ((uint2*)outbuf)[node * 32 + f4] = f4_to_h4(acc);
    } else {
        ((float4*)outbuf)[node * 32 + f4] = acc;
    }
}

// ---------------- fallback (atomic) path kernels ----------------
__global__ void deg_kernel(const void* ei, const int* flag, float* deg, int E) {
    int e = blockIdx.x * blockDim.x + threadIdx.x;
    if (e >= E) return;
    int src, dst;
    load_edge(ei, *flag, E, e, src, dst);
    atomicAdd(&deg[dst], 1.0f);
}

__global__ void dinv_kernel(float* deg) {
    int i = blockIdx.x * blockDim.x + threadIdx.x;
    if (i >= NN) return;
    float d = deg[i];
    deg[i] = (d > 0.0f) ? (1.0f / sqrtf(d)) : 0.0f;
}

template <bool RELU_IN>
__global__ void conv_atomic_kernel(const float* __restrict__ xin, const void* ei, const int* flag,
                                   const float* __restrict__ dinv, float* __restrict__ yout, int E) {
    int gid = blockIdx.x * blockDim.x + threadIdx.x;
    int e  = gid >> 5;
    int f4 = gid & 31;
    if (e >= E) return;
    int src, dst;
    load_edge(ei, *flag, E, e, src, dst);
    float w = dinv[src] * dinv[dst];
    float4 v = ((const float4*)xin)[src * 32 + f4];
    if (RELU_IN) v = relu4(v);
    float* o = yout + (size_t)dst * FEAT + f4 * 4;
    atomicAdd(o + 0, v.x * w);
    atomicAdd(o + 1, v.y * w);
    atomicAdd(o + 2, v.z * w);
    atomicAdd(o + 3, v.w * w);
}

__global__ void relu_kernel(float4* buf, int n4) {
    int i = blockIdx.x * blockDim.x + threadIdx.x;
    if (i >= n4) return;
    buf[i] = relu4(buf[i]);
}

extern "C" void kernel_launch(void* const* d_in, const int* in_sizes, int n_in,
                              void* d_out, int out_size, void* d_ws, size_t ws_size,
                              hipStream_t stream) {
    const float* x  = (const float*)d_in[0];
    const void*  ei = d_in[1];
    const int E = in_sizes[1] / 2;

    float* out = (float*)d_out;
    char*  ws  = (char*)d_ws;

    const size_t feat_bytes  = (size_t)NN * FEAT * sizeof(float);
    const size_t half_bytes  = (size_t)NN * FEAT * sizeof(unsigned short);
    const int NB = (NN + 255) / 256;
    const int N4 = NN * 32;

    // ws layout (CSR fp16 path)
    const size_t OFF_FLAG = 0;
    const size_t OFF_HIST = 1024;
    const size_t OFF_DINV = OFF_HIST + (((size_t)NN * 4 + 255) & ~255ull);
    const size_t OFF_ROWP = OFF_DINV + (((size_t)NN * 4 + 255) & ~255ull);
    const size_t OFF_BSUM = OFF_ROWP + ((((size_t)NN + 1) * 4 + 255) & ~255ull);
    const size_t OFF_RNK  = OFF_BSUM + ((1024 * 4 + 255) & ~255ull);
    const size_t OFF_COL  = OFF_RNK + (((size_t)E * 4 + 255) & ~255ull);
    const size_t OFF_HA   = OFF_COL + (((size_t)E * 4 + 255) & ~255ull);
    const size_t OFF_HB   = OFF_HA + ((half_bytes + 255) & ~255ull);
    const size_t NEEDED   = OFF_HB + half_bytes;

    int* flag = (int*)(ws + OFF_FLAG);

    if (ws_size >= NEEDED) {
        int*   hist = (int*)(ws + OFF_HIST);
        float* dinv = (float*)(ws + OFF_DINV);
        int*   rowp = (int*)(ws + OFF_ROWP);
        int*   bsum = (int*)(ws + OFF_BSUM);
        int*   rank = (int*)(ws + OFF_RNK);
        int*   col  = (int*)(ws + OFF_COL);
        uint2* hA   = (uint2*)(ws + OFF_HA);
        uint2* hB   = (uint2*)(ws + OFF_HB);

        init_kernel<<<NB, 256, 0, stream>>>((const unsigned int*)ei, flag, hist, NN);

        const int e4_blocks = (E / 4 + 255) / 256 + 1;
        // pass 1: ranks (hist becomes degrees)
        rank_kernel<<<e4_blocks, 256, 0, stream>>>(ei, flag, hist, rank, E);
        scan_local_kernel<<<NB, 256, 0, stream>>>(hist, rowp, bsum, dinv, NN);
        // cvt needs dinv (ready after scan_local); overlaps the scan tail
        cvt_f2h_kernel<<<(N4 + 255) / 256, 256, 0, stream>>>((const float4*)x, dinv, hA, N4);
        scan_bsum_kernel<<<1, 1024, 0, stream>>>(bsum, NB);
        scan_add_kernel<<<NB, 256, 0, stream>>>(rowp, bsum, rowp, NN, E);
        // pass 2: placement (no atomics, nt stores)
        place_kernel<<<e4_blocks, 256, 0, stream>>>(ei, flag, rowp, rank, col, E);

        const int conv_blocks = (NN * 32 + 255) / 256;
        conv_h_kernel<true><<<conv_blocks, 256, 0, stream>>>(hA, rowp, col, dinv, hB);
        conv_h_kernel<true><<<conv_blocks, 256, 0, stream>>>(hB, rowp, col, dinv, hA);
        conv_h_kernel<false><<<conv_blocks, 256, 0, stream>>>(hA, rowp, col, dinv, out);
    } else {
        // fallback: atomic fp32 implementation
        float* dinv = (float*)(ws + 1024);
        float* y    = (float*)(ws + 262144);

        hipMemsetAsync(dinv, 0, NN * sizeof(float), stream);
        hipMemsetAsync(out, 0, feat_bytes, stream);
        hipMemsetAsync(y, 0, feat_bytes, stream);

        init_kernel<<<1, 256, 0, stream>>>((const unsigned int*)ei, flag, (int*)(ws + 512), 256);
        deg_kernel<<<(E + 255) / 256, 256, 0, stream>>>(ei, flag, dinv, E);
        dinv_kernel<<<(NN + 255) / 256, 256, 0, stream>>>(dinv);

        const int conv_blocks = (int)(((size_t)E * 32 + 255) / 256);
        conv_atomic_kernel<false><<<conv_blocks, 256, 0, stream>>>(x, ei, flag, dinv, out, E);
        conv_atomic_kernel<true><<<conv_blocks, 256, 0, stream>>>(out, ei, flag, dinv, y, E);
        hipMemsetAsync(out, 0, feat_bytes, stream);
        conv_atomic_kernel<true><<<conv_blocks, 256, 0, stream>>>(y, ei, flag, dinv, out, E);
        relu_kernel<<<(out_size / 4 + 255) / 256, 256, 0, stream>>>((float4*)out, out_size / 4);
    }
}